// Round 1
// baseline (1266.942 us; speedup 1.0000x reference)
//
#include <hip/hip_runtime.h>
#include <hip/hip_bf16.h>
#include <math.h>

// Problem constants
//  D=2048, H=16, KVH=8, DH=128, B=4, L=2048, T=8192, C=64, chunks=32, chains=B*H=64
#define RSQRT_DH 0.08838834764831845f

typedef __attribute__((ext_vector_type(8))) short short8;
typedef __attribute__((ext_vector_type(4))) float floatx4;

static __device__ __forceinline__ float bf2f(unsigned short u) {
  return __uint_as_float(((unsigned int)u) << 16);
}
static __device__ __forceinline__ unsigned short f2bf(float f) {
  unsigned int x = __float_as_uint(f);
  return (unsigned short)((x + 0x7fffu + ((x >> 16) & 1u)) >> 16);
}
static __device__ __forceinline__ ushort4 f4bf(float a, float b, float c, float d) {
  ushort4 r; r.x = f2bf(a); r.y = f2bf(b); r.z = f2bf(c); r.w = f2bf(d); return r;
}

// ---------------- K0: fp32 -> bf16 convert (hidden_states) ----------------
__launch_bounds__(256)
__global__ void k_cvt(const float* __restrict__ in, unsigned short* __restrict__ out, int n4) {
  int i = blockIdx.x * 256 + threadIdx.x;
  if (i >= n4) return;
  float4 v = ((const float4*)in)[i];
  ((ushort4*)out)[i] = f4bf(v.x, v.y, v.z, v.w);
}

// ---------------- K1: W (2048 x 4096 f32) -> Wt (4096 x 2048 bf16), transposed
__launch_bounds__(256)
__global__ void k_cvt_wt(const float* __restrict__ W, unsigned short* __restrict__ Wt) {
  __shared__ float tile[32][33];
  int t = threadIdx.x;
  int c = t & 31, r = t >> 5;            // r in 0..7
  int bx = blockIdx.x, by = blockIdx.y;  // bx: n-tile, by: k-tile
#pragma unroll
  for (int j = 0; j < 4; ++j)
    tile[r + j * 8][c] = W[(size_t)(by * 32 + r + j * 8) * 4096 + bx * 32 + c];
  __syncthreads();
#pragma unroll
  for (int j = 0; j < 4; ++j)
    Wt[(size_t)(bx * 32 + r + j * 8) * 2048 + by * 32 + c] = f2bf(tile[c][r + j * 8]);
}

// ---------------- K2: bf16 MFMA GEMM, M=8192 N=4096 K=2048, fused activations
// A = hs_bf16 (8192x2048 row-major), Bt = Wt (4096x2048 row-major, i.e. W^T)
__launch_bounds__(256)
__global__ void k_gemm(const unsigned short* __restrict__ A,
                       const unsigned short* __restrict__ Bt,
                       const float* __restrict__ bias,
                       unsigned short* __restrict__ qb,
                       unsigned short* __restrict__ kb,
                       unsigned short* __restrict__ vb,
                       float* __restrict__ gf) {
  __shared__ unsigned short lds_a[128 * 72];  // +8 pad: 2-way banks only
  __shared__ unsigned short lds_b[128 * 72];
  const int t = threadIdx.x;
  const int m0 = blockIdx.y * 128;
  const int n0 = blockIdx.x * 128;
  const int w = t >> 6, l = t & 63;
  const int wr = w >> 1, wc = w & 1;       // 2x2 waves of 64x64
  const int lrow = t >> 1, lcol = (t & 1) * 32;

  floatx4 acc[4][4] = {};
  const unsigned short* ap = A + (size_t)(m0 + lrow) * 2048 + lcol;
  const unsigned short* bp = Bt + (size_t)(n0 + lrow) * 2048 + lcol;

  for (int kt = 0; kt < 2048; kt += 64) {
    __syncthreads();
    const uint4* ag = (const uint4*)(ap + kt);
    const uint4* bg = (const uint4*)(bp + kt);
    uint4 a0 = ag[0], a1 = ag[1], a2 = ag[2], a3 = ag[3];
    uint4 b0 = bg[0], b1 = bg[1], b2 = bg[2], b3 = bg[3];
    uint4* as = (uint4*)(lds_a + lrow * 72 + lcol);
    uint4* bs = (uint4*)(lds_b + lrow * 72 + lcol);
    as[0] = a0; as[1] = a1; as[2] = a2; as[3] = a3;
    bs[0] = b0; bs[1] = b1; bs[2] = b2; bs[3] = b3;
    __syncthreads();
#pragma unroll
    for (int ks = 0; ks < 2; ++ks) {
      short8 af[4], bf[4];
      const int krow = ks * 32 + (l >> 4) * 8;
#pragma unroll
      for (int ti = 0; ti < 4; ++ti) {
        int m = wr * 64 + ti * 16 + (l & 15);
        af[ti] = *(const short8*)(lds_a + m * 72 + krow);
      }
#pragma unroll
      for (int tj = 0; tj < 4; ++tj) {
        int n = wc * 64 + tj * 16 + (l & 15);
        bf[tj] = *(const short8*)(lds_b + n * 72 + krow);
      }
#pragma unroll
      for (int ti = 0; ti < 4; ++ti)
#pragma unroll
        for (int tj = 0; tj < 4; ++tj)
          acc[ti][tj] = __builtin_amdgcn_mfma_f32_16x16x32_bf16(af[ti], bf[tj], acc[ti][tj], 0, 0, 0);
    }
  }
  // Epilogue: qkv split + activations. D mapping: row=(l>>4)*4+r, col=l&15.
#pragma unroll
  for (int ti = 0; ti < 4; ++ti) {
#pragma unroll
    for (int tj = 0; tj < 4; ++tj) {
      const int n = n0 + wc * 64 + tj * 16 + (l & 15);
      const float bn = bias[n];
#pragma unroll
      for (int r = 0; r < 4; ++r) {
        const int m = m0 + wr * 64 + ti * 16 + ((l >> 4) * 4) + r;
        float val = acc[ti][tj][r] + bn;
        if (n < 2048) {
          qb[(size_t)m * 2048 + n] = f2bf(fmaxf(val, 0.f) * RSQRT_DH);
        } else if (n < 3072) {
          float s = 1.f / (1.f + __expf(-val));
          s = fminf(s, 0.95f);
          size_t idx = (size_t)m * 1024 + (n - 2048);
          kb[idx] = f2bf(s);
          gf[idx] = log1pf(-s);
        } else {
          vb[(size_t)m * 1024 + (n - 3072)] = f2bf(val);
        }
      }
    }
  }
}

// ---------------- K3: per-chunk P = kg^T @ v and b_last; grid (chunk=32, chain=64)
__launch_bounds__(256)
__global__ void k_phaseA(const unsigned short* __restrict__ kb,
                         const unsigned short* __restrict__ vb,
                         const float* __restrict__ gf,
                         float* __restrict__ blast,
                         unsigned short* __restrict__ Pb) {
  __shared__ float sBc[64 * 128];  // g then in-place cumsum -> Bc
  __shared__ float sKg[64 * 128];
  const int t = threadIdx.x;
  const int chunk = blockIdx.x, chain = blockIdx.y;
  const int b = chain >> 4, h = chain & 15, kvh = h >> 1;
  const int t0 = b * 2048 + chunk * 64;

#pragma unroll
  for (int rep = 0; rep < 8; ++rep) {
    int e = rep * 256 + t;  // float4 index
    int i = e >> 5, d4 = e & 31;
    *(float4*)(sBc + i * 128 + d4 * 4) =
        *(const float4*)(gf + (size_t)(t0 + i) * 1024 + kvh * 128 + d4 * 4);
  }
  __syncthreads();
  if (t < 128) {
    float run = sBc[t];
#pragma unroll 1
    for (int i = 1; i < 64; ++i) { run += sBc[i * 128 + t]; sBc[i * 128 + t] = run; }
    blast[((size_t)chain * 32 + chunk) * 128 + t] = run;
  }
  __syncthreads();
#pragma unroll
  for (int rep = 0; rep < 32; ++rep) {
    int e = rep * 256 + t;
    int i = e >> 7, d = e & 127;
    float kk = bf2f(kb[(size_t)(t0 + i) * 1024 + kvh * 128 + d]);
    sKg[e] = kk * __expf(sBc[63 * 128 + d] - sBc[e]);
  }
  __syncthreads();
  // P[k][v] += kg[i][k]*v[i][v]; thread tile 4k x 16v
  const int kq = t >> 3, vq = t & 7;
  const int kd0 = kq * 4, vd0 = vq * 16;
  float acc[4][16] = {};
  const unsigned short* vrow = vb + (size_t)t0 * 1024 + kvh * 128 + vd0;
  for (int i = 0; i < 64; ++i) {
    float4 kg4 = *(const float4*)(sKg + i * 128 + kd0);
    float ka[4] = {kg4.x, kg4.y, kg4.z, kg4.w};
    ushort4 v0 = *(const ushort4*)(vrow + (size_t)i * 1024);
    ushort4 v1 = *(const ushort4*)(vrow + (size_t)i * 1024 + 4);
    ushort4 v2 = *(const ushort4*)(vrow + (size_t)i * 1024 + 8);
    ushort4 v3 = *(const ushort4*)(vrow + (size_t)i * 1024 + 12);
    float vf[16] = {bf2f(v0.x), bf2f(v0.y), bf2f(v0.z), bf2f(v0.w),
                    bf2f(v1.x), bf2f(v1.y), bf2f(v1.z), bf2f(v1.w),
                    bf2f(v2.x), bf2f(v2.y), bf2f(v2.z), bf2f(v2.w),
                    bf2f(v3.x), bf2f(v3.y), bf2f(v3.z), bf2f(v3.w)};
#pragma unroll
    for (int r = 0; r < 4; ++r)
#pragma unroll
      for (int j = 0; j < 16; ++j) acc[r][j] += ka[r] * vf[j];
  }
  size_t pbase = ((size_t)chain * 32 + chunk) * 16384;
#pragma unroll
  for (int r = 0; r < 4; ++r)
#pragma unroll
    for (int j4 = 0; j4 < 4; ++j4)
      *(ushort4*)(Pb + pbase + (size_t)(kd0 + r) * 128 + vd0 + j4 * 4) =
          f4bf(acc[r][j4 * 4], acc[r][j4 * 4 + 1], acc[r][j4 * 4 + 2], acc[r][j4 * 4 + 3]);
}

// ---------------- K4: state scan, S checkpoints (state at chunk START), grid (16, 64)
__launch_bounds__(256)
__global__ void k_scan(const float* __restrict__ kv_cache,
                       const int* __restrict__ sidx,
                       const float* __restrict__ blast,
                       const unsigned short* __restrict__ Pb,
                       unsigned short* __restrict__ Sb) {
  const int t = threadIdx.x;
  const int part = blockIdx.x;   // 16 parts x 1024 elems
  const int chain = blockIdx.y;  // 64
  const int b = chain >> 4, h = chain & 15;
  const int e0 = part * 1024 + t * 4;
  const int kd = e0 >> 7;
  const int slot = sidx[b];
  float4 s = *(const float4*)(kv_cache + ((size_t)slot * 16 + h) * 16384 + e0);
#pragma unroll 1
  for (int c = 0; c < 32; ++c) {
    *(ushort4*)(Sb + ((size_t)c * 64 + chain) * 16384 + e0) = f4bf(s.x, s.y, s.z, s.w);
    float eb = __expf(blast[((size_t)chain * 32 + c) * 128 + kd]);
    ushort4 p = *(const ushort4*)(Pb + ((size_t)chain * 32 + c) * 16384 + e0);
    s.x = s.x * eb + bf2f(p.x);
    s.y = s.y * eb + bf2f(p.y);
    s.z = s.z * eb + bf2f(p.z);
    s.w = s.w * eb + bf2f(p.w);
  }
}

// ---------------- K5: output = qe @ S + (masked A) @ v ; grid (chunk=32, chain=64)
__launch_bounds__(256)
__global__ void k_output(const unsigned short* __restrict__ qb,
                         const unsigned short* __restrict__ kb,
                         const unsigned short* __restrict__ vb,
                         const float* __restrict__ gf,
                         const unsigned short* __restrict__ Sb,
                         float* __restrict__ out) {
  __shared__ float sBc[64 * 128];
  __shared__ float sQE[64 * 128];  // first 16KB reused as A[64][64] after o_inter
  float* sA = sQE;
  const int t = threadIdx.x;
  const int chunk = blockIdx.x, chain = blockIdx.y;
  const int b = chain >> 4, h = chain & 15, kvh = h >> 1;
  const int t0 = b * 2048 + chunk * 64;

  // g -> Bc (in-place cumsum)
#pragma unroll
  for (int rep = 0; rep < 8; ++rep) {
    int e = rep * 256 + t;
    int i = e >> 5, d4 = e & 31;
    *(float4*)(sBc + i * 128 + d4 * 4) =
        *(const float4*)(gf + (size_t)(t0 + i) * 1024 + kvh * 128 + d4 * 4);
  }
  __syncthreads();
  if (t < 128) {
    float run = sBc[t];
#pragma unroll 1
    for (int i = 1; i < 64; ++i) { run += sBc[i * 128 + t]; sBc[i * 128 + t] = run; }
  }
  __syncthreads();

  // qe = q * exp(Bc)
#pragma unroll
  for (int rep = 0; rep < 32; ++rep) {
    int e = rep * 256 + t;
    int i = e >> 7, d = e & 127;
    float qv = bf2f(qb[(size_t)(t0 + i) * 2048 + h * 128 + d]);
    sQE[e] = qv * __expf(sBc[e]);
  }
  __syncthreads();

  // o_inter = qe @ S ; thread tile 4i x 8v
  const int ig = t >> 4, vg = t & 15;
  const int i0 = ig * 4, vd0 = vg * 8;
  float o[4][8] = {};
  const unsigned short* sp = Sb + ((size_t)chunk * 64 + chain) * 16384 + vd0;
  for (int k = 0; k < 128; ++k) {
    ushort4 s0 = *(const ushort4*)(sp + (size_t)k * 128);
    ushort4 s1 = *(const ushort4*)(sp + (size_t)k * 128 + 4);
    float sf[8] = {bf2f(s0.x), bf2f(s0.y), bf2f(s0.z), bf2f(s0.w),
                   bf2f(s1.x), bf2f(s1.y), bf2f(s1.z), bf2f(s1.w)};
#pragma unroll
    for (int r = 0; r < 4; ++r) {
      float qe = sQE[(i0 + r) * 128 + k];
#pragma unroll
      for (int j = 0; j < 8; ++j) o[r][j] += qe * sf[j];
    }
  }
  __syncthreads();  // all sQE reads done before aliasing as A

  // A[i][j] = sum_k q_i k_j exp(Bc_i - Bc_j), j<=i ; thread tile 4i x 4j
  {
    const int iq = t >> 4, jq = t & 15;
    const unsigned short* qrow = qb + (size_t)t0 * 2048 + h * 128;
    const unsigned short* krow = kb + (size_t)t0 * 1024 + kvh * 128;
    float a4[4][4] = {};
    for (int k = 0; k < 128; ++k) {
      float qv[4], kv[4], bi[4], bj[4];
#pragma unroll
      for (int r = 0; r < 4; ++r) {
        qv[r] = bf2f(qrow[(size_t)(iq * 4 + r) * 2048 + k]);
        bi[r] = sBc[(iq * 4 + r) * 128 + k];
        kv[r] = bf2f(krow[(size_t)(jq * 4 + r) * 1024 + k]);
        bj[r] = sBc[(jq * 4 + r) * 128 + k];
      }
#pragma unroll
      for (int r = 0; r < 4; ++r)
#pragma unroll
        for (int c2 = 0; c2 < 4; ++c2)
          a4[r][c2] += qv[r] * kv[c2] * __expf(fminf(bi[r] - bj[c2], 0.f));
    }
#pragma unroll
    for (int r = 0; r < 4; ++r)
#pragma unroll
      for (int c2 = 0; c2 < 4; ++c2) {
        int i = iq * 4 + r, j = jq * 4 + c2;
        sA[i * 64 + j] = (j <= i) ? a4[r][c2] : 0.f;
      }
  }
  __syncthreads();

  // o += A @ v
  const unsigned short* vrow = vb + (size_t)t0 * 1024 + kvh * 128 + vd0;
  for (int j = 0; j < 64; ++j) {
    ushort4 v0 = *(const ushort4*)(vrow + (size_t)j * 1024);
    ushort4 v1 = *(const ushort4*)(vrow + (size_t)j * 1024 + 4);
    float vf[8] = {bf2f(v0.x), bf2f(v0.y), bf2f(v0.z), bf2f(v0.w),
                   bf2f(v1.x), bf2f(v1.y), bf2f(v1.z), bf2f(v1.w)};
#pragma unroll
    for (int r = 0; r < 4; ++r) {
      float av = sA[(i0 + r) * 64 + j];
#pragma unroll
      for (int c2 = 0; c2 < 8; ++c2) o[r][c2] += av * vf[c2];
    }
  }

  // store (T, H*DH) fp32
#pragma unroll
  for (int r = 0; r < 4; ++r) {
    float* op = out + (size_t)(t0 + i0 + r) * 2048 + h * 128 + vd0;
    ((float4*)op)[0] = make_float4(o[r][0], o[r][1], o[r][2], o[r][3]);
    ((float4*)op)[1] = make_float4(o[r][4], o[r][5], o[r][6], o[r][7]);
  }
}

extern "C" void kernel_launch(void* const* d_in, const int* in_sizes, int n_in,
                              void* d_out, int out_size, void* d_ws, size_t ws_size,
                              hipStream_t stream) {
  (void)in_sizes; (void)n_in; (void)out_size; (void)ws_size;
  const float* hs   = (const float*)d_in[0];
  const float* W    = (const float*)d_in[1];
  const float* bias = (const float*)d_in[2];
  const float* kvc  = (const float*)d_in[3];
  const int*   sidx = (const int*)d_in[4];

  char* ws = (char*)d_ws;
  // Layout (bytes). Sb overlaps the transient bf16 conversion buffers (dead after GEMM).
  unsigned short* Sb  = (unsigned short*)(ws + 0);          // 67,108,864 (32 chunk ckpts, bf16)
  unsigned short* hsb = (unsigned short*)(ws + 0);          // 33,554,432 (transient)
  unsigned short* wtb = (unsigned short*)(ws + 33554432);   // 16,777,216 (transient)
  unsigned short* qb  = (unsigned short*)(ws + 67108864);   // 33,554,432
  unsigned short* kb  = (unsigned short*)(ws + 100663296);  // 16,777,216
  unsigned short* vb  = (unsigned short*)(ws + 117440512);  // 16,777,216
  float*          gf  = (float*)(ws + 134217728);           // 33,554,432
  float*          bl  = (float*)(ws + 167772160);           // 1,048,576  -> total 168,820,736
  unsigned short* Pb  = (unsigned short*)d_out;             // P staged in d_out (consumed before K5)
  float* out = (float*)d_out;

  k_cvt<<<dim3(16384), dim3(256), 0, stream>>>(hs, hsb, 16777216 / 4);
  k_cvt_wt<<<dim3(128, 64), dim3(256), 0, stream>>>(W, wtb);
  k_gemm<<<dim3(32, 64), dim3(256), 0, stream>>>(hsb, wtb, bias, qb, kb, vb, gf);
  k_phaseA<<<dim3(32, 64), dim3(256), 0, stream>>>(kb, vb, gf, bl, Pb);
  k_scan<<<dim3(16, 64), dim3(256), 0, stream>>>(kvc, sidx, bl, Pb, Sb);
  k_output<<<dim3(32, 64), dim3(256), 0, stream>>>(qb, kb, vb, gf, Sb, out);
}

// Round 2
// 616.883 us; speedup vs baseline: 2.0538x; 2.0538x over previous
//
#include <hip/hip_runtime.h>
#include <hip/hip_bf16.h>
#include <math.h>

// Problem constants
//  D=2048, H=16, KVH=8, DH=128, B=4, L=2048, T=8192, C=64, chunks=32, chains=B*H=64
#define RSQRT_DH 0.08838834764831845f

typedef __attribute__((ext_vector_type(8))) short short8;
typedef __attribute__((ext_vector_type(4))) float floatx4;

static __device__ __forceinline__ float bf2f(unsigned short u) {
  return __uint_as_float(((unsigned int)u) << 16);
}
static __device__ __forceinline__ unsigned short f2bf(float f) {
  unsigned int x = __float_as_uint(f);
  return (unsigned short)((x + 0x7fffu + ((x >> 16) & 1u)) >> 16);
}
static __device__ __forceinline__ ushort4 f4bf(float a, float b, float c, float d) {
  ushort4 r; r.x = f2bf(a); r.y = f2bf(b); r.z = f2bf(c); r.w = f2bf(d); return r;
}
// 8-byte-aligned LDS load of 8 bf16 (for stride-76 buffers)
static __device__ __forceinline__ short8 ld8u(const unsigned short* p) {
  short4 a = *(const short4*)p;
  short4 b = *(const short4*)(p + 4);
  short8 r;
  r[0] = a.x; r[1] = a.y; r[2] = a.z; r[3] = a.w;
  r[4] = b.x; r[5] = b.y; r[6] = b.z; r[7] = b.w;
  return r;
}

// ---------------- K0: fp32 -> bf16 convert (hidden_states) ----------------
__launch_bounds__(256)
__global__ void k_cvt(const float* __restrict__ in, unsigned short* __restrict__ out, int n4) {
  int i = blockIdx.x * 256 + threadIdx.x;
  if (i >= n4) return;
  float4 v = ((const float4*)in)[i];
  ((ushort4*)out)[i] = f4bf(v.x, v.y, v.z, v.w);
}

// ---------------- K1: W (2048 x 4096 f32) -> Wt (4096 x 2048 bf16), transposed
__launch_bounds__(256)
__global__ void k_cvt_wt(const float* __restrict__ W, unsigned short* __restrict__ Wt) {
  __shared__ float tile[32][33];
  int t = threadIdx.x;
  int c = t & 31, r = t >> 5;            // r in 0..7
  int bx = blockIdx.x, by = blockIdx.y;  // bx: n-tile, by: k-tile
#pragma unroll
  for (int j = 0; j < 4; ++j)
    tile[r + j * 8][c] = W[(size_t)(by * 32 + r + j * 8) * 4096 + bx * 32 + c];
  __syncthreads();
#pragma unroll
  for (int j = 0; j < 4; ++j)
    Wt[(size_t)(bx * 32 + r + j * 8) * 2048 + by * 32 + c] = f2bf(tile[c][r + j * 8]);
}

// ---------------- K2: bf16 MFMA GEMM, M=8192 N=4096 K=2048, fused activations
__launch_bounds__(256)
__global__ void k_gemm(const unsigned short* __restrict__ A,
                       const unsigned short* __restrict__ Bt,
                       const float* __restrict__ bias,
                       unsigned short* __restrict__ qb,
                       unsigned short* __restrict__ kb,
                       unsigned short* __restrict__ vb,
                       float* __restrict__ gf) {
  __shared__ unsigned short lds_a[128 * 72];
  __shared__ unsigned short lds_b[128 * 72];
  const int t = threadIdx.x;
  const int m0 = blockIdx.y * 128;
  const int n0 = blockIdx.x * 128;
  const int w = t >> 6, l = t & 63;
  const int wr = w >> 1, wc = w & 1;
  const int lrow = t >> 1, lcol = (t & 1) * 32;

  floatx4 acc[4][4] = {};
  const unsigned short* ap = A + (size_t)(m0 + lrow) * 2048 + lcol;
  const unsigned short* bp = Bt + (size_t)(n0 + lrow) * 2048 + lcol;

  for (int kt = 0; kt < 2048; kt += 64) {
    __syncthreads();
    const uint4* ag = (const uint4*)(ap + kt);
    const uint4* bg = (const uint4*)(bp + kt);
    uint4 a0 = ag[0], a1 = ag[1], a2 = ag[2], a3 = ag[3];
    uint4 b0 = bg[0], b1 = bg[1], b2 = bg[2], b3 = bg[3];
    uint4* as = (uint4*)(lds_a + lrow * 72 + lcol);
    uint4* bs = (uint4*)(lds_b + lrow * 72 + lcol);
    as[0] = a0; as[1] = a1; as[2] = a2; as[3] = a3;
    bs[0] = b0; bs[1] = b1; bs[2] = b2; bs[3] = b3;
    __syncthreads();
#pragma unroll
    for (int ks = 0; ks < 2; ++ks) {
      short8 af[4], bf[4];
      const int krow = ks * 32 + (l >> 4) * 8;
#pragma unroll
      for (int ti = 0; ti < 4; ++ti) {
        int m = wr * 64 + ti * 16 + (l & 15);
        af[ti] = *(const short8*)(lds_a + m * 72 + krow);
      }
#pragma unroll
      for (int tj = 0; tj < 4; ++tj) {
        int n = wc * 64 + tj * 16 + (l & 15);
        bf[tj] = *(const short8*)(lds_b + n * 72 + krow);
      }
#pragma unroll
      for (int ti = 0; ti < 4; ++ti)
#pragma unroll
        for (int tj = 0; tj < 4; ++tj)
          acc[ti][tj] = __builtin_amdgcn_mfma_f32_16x16x32_bf16(af[ti], bf[tj], acc[ti][tj], 0, 0, 0);
    }
  }
#pragma unroll
  for (int ti = 0; ti < 4; ++ti) {
#pragma unroll
    for (int tj = 0; tj < 4; ++tj) {
      const int n = n0 + wc * 64 + tj * 16 + (l & 15);
      const float bn = bias[n];
#pragma unroll
      for (int r = 0; r < 4; ++r) {
        const int m = m0 + wr * 64 + ti * 16 + ((l >> 4) * 4) + r;
        float val = acc[ti][tj][r] + bn;
        if (n < 2048) {
          qb[(size_t)m * 2048 + n] = f2bf(fmaxf(val, 0.f) * RSQRT_DH);
        } else if (n < 3072) {
          float s = 1.f / (1.f + __expf(-val));
          s = fminf(s, 0.95f);
          size_t idx = (size_t)m * 1024 + (n - 2048);
          kb[idx] = f2bf(s);
          gf[idx] = log1pf(-s);
        } else {
          vb[(size_t)m * 1024 + (n - 3072)] = f2bf(val);
        }
      }
    }
  }
}

// ---------------- K3: per-chunk P = kg^T @ v and b_last; grid (chunk=32, chain=64)
__launch_bounds__(256)
__global__ void k_phaseA(const unsigned short* __restrict__ kb,
                         const unsigned short* __restrict__ vb,
                         const float* __restrict__ gf,
                         float* __restrict__ blast,
                         unsigned short* __restrict__ Pb) {
  __shared__ float sBc[64 * 128];
  __shared__ float sKg[64 * 128];
  const int t = threadIdx.x;
  const int chunk = blockIdx.x, chain = blockIdx.y;
  const int b = chain >> 4, h = chain & 15, kvh = h >> 1;
  const int t0 = b * 2048 + chunk * 64;

#pragma unroll
  for (int rep = 0; rep < 8; ++rep) {
    int e = rep * 256 + t;
    int i = e >> 5, d4 = e & 31;
    *(float4*)(sBc + i * 128 + d4 * 4) =
        *(const float4*)(gf + (size_t)(t0 + i) * 1024 + kvh * 128 + d4 * 4);
  }
  __syncthreads();
  if (t < 128) {
    float run = sBc[t];
    for (int i = 1; i < 64; ++i) { run += sBc[i * 128 + t]; sBc[i * 128 + t] = run; }
    blast[((size_t)chain * 32 + chunk) * 128 + t] = run;
  }
  __syncthreads();
#pragma unroll
  for (int rep = 0; rep < 32; ++rep) {
    int e = rep * 256 + t;
    int i = e >> 7, d = e & 127;
    float kk = bf2f(kb[(size_t)(t0 + i) * 1024 + kvh * 128 + d]);
    sKg[e] = kk * __expf(sBc[63 * 128 + d] - sBc[e]);
  }
  __syncthreads();
  const int kq = t >> 3, vq = t & 7;
  const int kd0 = kq * 4, vd0 = vq * 16;
  float acc[4][16] = {};
  const unsigned short* vrow = vb + (size_t)t0 * 1024 + kvh * 128 + vd0;
  for (int i = 0; i < 64; ++i) {
    float4 kg4 = *(const float4*)(sKg + i * 128 + kd0);
    float ka[4] = {kg4.x, kg4.y, kg4.z, kg4.w};
    ushort4 v0 = *(const ushort4*)(vrow + (size_t)i * 1024);
    ushort4 v1 = *(const ushort4*)(vrow + (size_t)i * 1024 + 4);
    ushort4 v2 = *(const ushort4*)(vrow + (size_t)i * 1024 + 8);
    ushort4 v3 = *(const ushort4*)(vrow + (size_t)i * 1024 + 12);
    float vf[16] = {bf2f(v0.x), bf2f(v0.y), bf2f(v0.z), bf2f(v0.w),
                    bf2f(v1.x), bf2f(v1.y), bf2f(v1.z), bf2f(v1.w),
                    bf2f(v2.x), bf2f(v2.y), bf2f(v2.z), bf2f(v2.w),
                    bf2f(v3.x), bf2f(v3.y), bf2f(v3.z), bf2f(v3.w)};
#pragma unroll
    for (int r = 0; r < 4; ++r)
#pragma unroll
      for (int j = 0; j < 16; ++j) acc[r][j] += ka[r] * vf[j];
  }
  size_t pbase = ((size_t)chain * 32 + chunk) * 16384;
#pragma unroll
  for (int r = 0; r < 4; ++r)
#pragma unroll
    for (int j4 = 0; j4 < 4; ++j4)
      *(ushort4*)(Pb + pbase + (size_t)(kd0 + r) * 128 + vd0 + j4 * 4) =
          f4bf(acc[r][j4 * 4], acc[r][j4 * 4 + 1], acc[r][j4 * 4 + 2], acc[r][j4 * 4 + 3]);
}

// ---------------- K4: state scan, S checkpoints (state at chunk START), grid (16, 64)
__launch_bounds__(256)
__global__ void k_scan(const float* __restrict__ kv_cache,
                       const int* __restrict__ sidx,
                       const float* __restrict__ blast,
                       const unsigned short* __restrict__ Pb,
                       unsigned short* __restrict__ Sb) {
  const int t = threadIdx.x;
  const int part = blockIdx.x;
  const int chain = blockIdx.y;
  const int b = chain >> 4, h = chain & 15;
  const int e0 = part * 1024 + t * 4;
  const int kd = e0 >> 7;
  const int slot = sidx[b];
  float4 s = *(const float4*)(kv_cache + ((size_t)slot * 16 + h) * 16384 + e0);
#pragma unroll 1
  for (int c = 0; c < 32; ++c) {
    *(ushort4*)(Sb + ((size_t)c * 64 + chain) * 16384 + e0) = f4bf(s.x, s.y, s.z, s.w);
    float eb = __expf(blast[((size_t)chain * 32 + c) * 128 + kd]);
    ushort4 p = *(const ushort4*)(Pb + ((size_t)chain * 32 + c) * 16384 + e0);
    s.x = s.x * eb + bf2f(p.x);
    s.y = s.y * eb + bf2f(p.y);
    s.z = s.z * eb + bf2f(p.z);
    s.w = s.w * eb + bf2f(p.w);
  }
}

// ---------------- K5 (MFMA rewrite): o = qe@S + (masked A)@v ; grid (chunk=32, chain=64)
// Sub-block factorization: for i-block I (16 rows), reference R_I[k]=Bc[16I-1][k]:
//   A_ij = (q_i e^{Bc_i-R_I}) . (k_j e^{R_I-Bc_j}),  exponents bounded by +/-48.
__launch_bounds__(256)
__global__ void k_output(const unsigned short* __restrict__ qb,
                         const unsigned short* __restrict__ kb,
                         const unsigned short* __restrict__ vb,
                         const float* __restrict__ gf,
                         const unsigned short* __restrict__ Sb,
                         float* __restrict__ out) {
  __shared__ float sBc[64 * 128];              // 32 KB, live whole kernel
  __shared__ unsigned short sR3[11136];        // 22272 B, phase-overlaid
  unsigned short* sA   = sR3;                  // [64][72]  (ph4 out, ph5 in)
  unsigned short* sKE  = sR3 + 4608;           // [32][136] (ph4)
  unsigned short* sQE2 = sR3 + 4608 + 4352;    // [16][136] (ph4)
  unsigned short* sQE0 = sR3;                  // [64][72]  (ph3, aliases sA)
  unsigned short* sSt  = sR3 + 4608;           // [64][76]  (ph3, aliases sKE)
  unsigned short* sVt  = sR3 + 4608;           // [64][76]  (ph5, aliases sKE)

  const int t = threadIdx.x;
  const int w = t >> 6, l = t & 63;
  const int lr = l & 15, quad = l >> 4;
  const int chunk = blockIdx.x, chain = blockIdx.y;
  const int b = chain >> 4, h = chain & 15, kvh = h >> 1;
  const int t0 = b * 2048 + chunk * 64;
  const size_t sbase = ((size_t)chunk * 64 + chain) * 16384;

  // ---- ph1: Bc = cumsum(g) ----
#pragma unroll
  for (int rep = 0; rep < 8; ++rep) {
    int e = rep * 256 + t, i = e >> 5, d4 = e & 31;
    *(float4*)(sBc + i * 128 + d4 * 4) =
        *(const float4*)(gf + (size_t)(t0 + i) * 1024 + kvh * 128 + d4 * 4);
  }
  __syncthreads();
  if (t < 128) {
    float run = sBc[t];
#pragma unroll
    for (int i = 1; i < 64; ++i) { run += sBc[i * 128 + t]; sBc[i * 128 + t] = run; }
  }

  floatx4 o[8];
#pragma unroll
  for (int i = 0; i < 8; ++i) o[i] = 0.f;

  // ---- ph3: o_inter = (q*exp(Bc)) @ S, k- and v-halved ----
#pragma unroll
  for (int kh = 0; kh < 2; ++kh) {
    __syncthreads();
    // stage QE0: 64 rows x 64 k (k-half), stride 72
#pragma unroll
    for (int rep = 0; rep < 2; ++rep) {
      int idx = rep * 256 + t;
      int i = idx >> 3, g = idx & 7;
      int k0 = kh * 64 + g * 8;
      short8 q8 = *(const short8*)(qb + (size_t)(t0 + i) * 2048 + h * 128 + k0);
      short8 r;
#pragma unroll
      for (int u = 0; u < 8; ++u)
        r[u] = (short)f2bf(bf2f((unsigned short)q8[u]) * __expf(sBc[i * 128 + k0 + u]));
      *(short8*)(sQE0 + i * 72 + g * 8) = r;
    }
#pragma unroll
    for (int vh = 0; vh < 2; ++vh) {
      __syncthreads();
      // stage St' = S^T half: [v_local 64][k_local 64] stride 76
#pragma unroll
      for (int rep = 0; rep < 2; ++rep) {
        int idx = rep * 256 + t;
        int kl = idx >> 3, g = idx & 7;
        short8 s8 = *(const short8*)(Sb + sbase + (size_t)(kh * 64 + kl) * 128 + vh * 64 + g * 8);
#pragma unroll
        for (int u = 0; u < 8; ++u) sSt[(g * 8 + u) * 76 + kl] = (unsigned short)s8[u];
      }
      __syncthreads();
      short8 af0 = *(const short8*)(sQE0 + (w * 16 + lr) * 72 + quad * 8);
      short8 af1 = *(const short8*)(sQE0 + (w * 16 + lr) * 72 + 32 + quad * 8);
#pragma unroll
      for (int tv = 0; tv < 4; ++tv) {
        const unsigned short* bp = sSt + (tv * 16 + lr) * 76 + quad * 8;
        short8 bf0 = ld8u(bp);
        short8 bf1 = ld8u(bp + 32);
        o[vh * 4 + tv] = __builtin_amdgcn_mfma_f32_16x16x32_bf16(af0, bf0, o[vh * 4 + tv], 0, 0, 0);
        o[vh * 4 + tv] = __builtin_amdgcn_mfma_f32_16x16x32_bf16(af1, bf1, o[vh * 4 + tv], 0, 0, 0);
      }
    }
  }

  // ---- ph4: A (masked, factorized), into sA bf16 [64][72] ----
  __syncthreads();
  for (int idx = t; idx < 576; idx += 256)
    *(short8*)(sA + idx * 8) = (short8)0;
#pragma unroll
  for (int I = 0; I < 4; ++I) {
    const float* Rrow = (I > 0) ? (sBc + (I * 16 - 1) * 128) : nullptr;
    for (int base = 0; base < (I + 1) * 16; base += 32) {
      int nrows = min(32, (I + 1) * 16 - base);
      __syncthreads();
      // stage KE_I rows [base, base+nrows), full k=128, stride 136
      int ngroups = nrows * 16;
      for (int idx = t; idx < ngroups; idx += 256) {
        int jl = idx >> 4, g = idx & 15;
        int j = base + jl, k0 = g * 8;
        short8 k8 = *(const short8*)(kb + (size_t)(t0 + j) * 1024 + kvh * 128 + k0);
        short8 r;
#pragma unroll
        for (int u = 0; u < 8; ++u) {
          int k = k0 + u;
          float Rk = Rrow ? Rrow[k] : 0.f;
          r[u] = (short)f2bf(bf2f((unsigned short)k8[u]) * __expf(Rk - sBc[j * 128 + k]));
        }
        *(short8*)(sKE + jl * 136 + k0) = r;
      }
      if (base == 0) {
        // stage QE2_I: 16 rows, shifted by R_I
        {
          int idx = t;  // exactly 256 groups
          int il = idx >> 4, g = idx & 15;
          int i = I * 16 + il, k0 = g * 8;
          short8 q8 = *(const short8*)(qb + (size_t)(t0 + i) * 2048 + h * 128 + k0);
          short8 r;
#pragma unroll
          for (int u = 0; u < 8; ++u) {
            int k = k0 + u;
            float Rk = Rrow ? Rrow[k] : 0.f;
            r[u] = (short)f2bf(bf2f((unsigned short)q8[u]) * __expf(sBc[i * 128 + k] - Rk));
          }
          *(short8*)(sQE2 + il * 136 + k0) = r;
        }
      }
      __syncthreads();
      const int J = w;
      if (J * 16 >= base && J * 16 < base + nrows) {
        floatx4 a4 = {};
#pragma unroll
        for (int ks = 0; ks < 4; ++ks) {
          short8 afr = *(const short8*)(sQE2 + lr * 136 + ks * 32 + quad * 8);
          short8 bfr = *(const short8*)(sKE + (J * 16 - base + lr) * 136 + ks * 32 + quad * 8);
          a4 = __builtin_amdgcn_mfma_f32_16x16x32_bf16(afr, bfr, a4, 0, 0, 0);
        }
#pragma unroll
        for (int r = 0; r < 4; ++r) {
          int il = quad * 4 + r;
          float v = ((J < I) || (lr <= il)) ? a4[r] : 0.f;
          sA[(I * 16 + il) * 72 + J * 16 + lr] = f2bf(v);
        }
      }
    }
  }

  // ---- ph5: o += A @ v, v-halved ----
  __syncthreads();
  short8 aA0 = *(const short8*)(sA + (w * 16 + lr) * 72 + quad * 8);
  short8 aA1 = *(const short8*)(sA + (w * 16 + lr) * 72 + 32 + quad * 8);
#pragma unroll
  for (int vh = 0; vh < 2; ++vh) {
    if (vh) __syncthreads();
    // stage Vt = v^T half: [vd_local 64][j 64] stride 76
#pragma unroll
    for (int rep = 0; rep < 2; ++rep) {
      int idx = rep * 256 + t;
      int j = idx >> 3, g = idx & 7;
      short8 v8 = *(const short8*)(vb + (size_t)(t0 + j) * 1024 + kvh * 128 + vh * 64 + g * 8);
#pragma unroll
      for (int u = 0; u < 8; ++u) sVt[(g * 8 + u) * 76 + j] = (unsigned short)v8[u];
    }
    __syncthreads();
#pragma unroll
    for (int tv = 0; tv < 4; ++tv) {
      const unsigned short* bp = sVt + (tv * 16 + lr) * 76 + quad * 8;
      short8 b0 = ld8u(bp);
      short8 b1 = ld8u(bp + 32);
      o[vh * 4 + tv] = __builtin_amdgcn_mfma_f32_16x16x32_bf16(aA0, b0, o[vh * 4 + tv], 0, 0, 0);
      o[vh * 4 + tv] = __builtin_amdgcn_mfma_f32_16x16x32_bf16(aA1, b1, o[vh * 4 + tv], 0, 0, 0);
    }
  }

  // ---- epilogue: D layout row=quad*4+r, col=lr ----
#pragma unroll
  for (int tv8 = 0; tv8 < 8; ++tv8) {
    int col = (tv8 >> 2) * 64 + (tv8 & 3) * 16 + lr;
#pragma unroll
    for (int r = 0; r < 4; ++r) {
      int i = w * 16 + quad * 4 + r;
      out[(size_t)(t0 + i) * 2048 + h * 128 + col] = o[tv8][r];
    }
  }
}

extern "C" void kernel_launch(void* const* d_in, const int* in_sizes, int n_in,
                              void* d_out, int out_size, void* d_ws, size_t ws_size,
                              hipStream_t stream) {
  (void)in_sizes; (void)n_in; (void)out_size; (void)ws_size;
  const float* hs   = (const float*)d_in[0];
  const float* W    = (const float*)d_in[1];
  const float* bias = (const float*)d_in[2];
  const float* kvc  = (const float*)d_in[3];
  const int*   sidx = (const int*)d_in[4];

  char* ws = (char*)d_ws;
  unsigned short* Sb  = (unsigned short*)(ws + 0);          // 67 MB (aliases hsb/wtb, dead after gemm)
  unsigned short* hsb = (unsigned short*)(ws + 0);
  unsigned short* wtb = (unsigned short*)(ws + 33554432);
  unsigned short* qb  = (unsigned short*)(ws + 67108864);
  unsigned short* kb  = (unsigned short*)(ws + 100663296);
  unsigned short* vb  = (unsigned short*)(ws + 117440512);
  float*          gf  = (float*)(ws + 134217728);
  float*          bl  = (float*)(ws + 167772160);
  unsigned short* Pb  = (unsigned short*)d_out;             // staged in d_out, consumed by k_scan
  float* out = (float*)d_out;

  k_cvt<<<dim3(16384), dim3(256), 0, stream>>>(hs, hsb, 16777216 / 4);
  k_cvt_wt<<<dim3(128, 64), dim3(256), 0, stream>>>(W, wtb);
  k_gemm<<<dim3(32, 64), dim3(256), 0, stream>>>(hsb, wtb, bias, qb, kb, vb, gf);
  k_phaseA<<<dim3(32, 64), dim3(256), 0, stream>>>(kb, vb, gf, bl, Pb);
  k_scan<<<dim3(16, 64), dim3(256), 0, stream>>>(kvc, sidx, bl, Pb, Sb);
  k_output<<<dim3(32, 64), dim3(256), 0, stream>>>(qb, kb, vb, gf, Sb, out);
}